// Round 4
// baseline (252.078 us; speedup 1.0000x reference)
//
#include <hip/hip_runtime.h>
#include <cstdint>

// B=8, T=1024, D=1024, H=16, hd=64
// prep (bf16 convert + weight transpose) -> QKV GEMM (256^2 8-phase-style,
// liveness-derived counted-vmcnt schedule) -> fused flash attention (r0
// version) -> proj GEMM (128^2 2-phase).
//
// QKV v9 schedule (derived, slot-liveness verified):
//  half-tile slots (16KB each, 2 gl2lds/thread):
//   Aalpha = A rows {0-63,128-191}   read p0,p1   (wave-group wm row-halves)
//   Abeta  = A rows {64-127,192-255} read p2,p3
//   Balpha = B rows {wn*64+0-31}     read p0,p3
//   Bbeta  = B rows {wn*64+32-63}    read p1,p2
//  phases (snake quadrants): p0=(mh0,nh0) p1=(mh0,nh1) p2=(mh1,nh1) p3=(mh1,nh0)
//  stage: p0->Balpha(t+1), p1->Abeta(t+1) [inactive buf];
//         p2->Aalpha(t+2), p3->Bbeta(t+2) [active buf, dead slots]
//  waits: vmcnt(8) end-p1 (Abeta(t), 4-phase slack);
//         vmcnt(6) end-p3 (Aalpha/Balpha/Bbeta(t+1), 4-6 phase slack).
//  tail: tile NT-2 waits 8/2 (stages p0,p1 only); NT-1 waits 0/none.

typedef __attribute__((ext_vector_type(8))) short bf16x8;
typedef __attribute__((ext_vector_type(4))) float f32x4;

__device__ __forceinline__ short f2b(float x) {
  unsigned u = __builtin_bit_cast(unsigned, x);
  u += 0x7fffu + ((u >> 16) & 1u);
  return (short)(u >> 16);
}

__device__ __forceinline__ void gl2lds16(short* l, const short* g) {
  __builtin_amdgcn_global_load_lds(
      (const __attribute__((address_space(1))) void*)g,
      (__attribute__((address_space(3))) void*)l, 16, 0, 0);
}

// ---------------- prep kernels ----------------

__global__ void f32_to_bf16_vec(const float* __restrict__ in,
                                short* __restrict__ outb, int n4) {
  int i = blockIdx.x * 256 + threadIdx.x;
  if (i >= n4) return;
  float4 v = ((const float4*)in)[i];
  short4 o;
  o.x = f2b(v.x); o.y = f2b(v.y); o.z = f2b(v.z); o.w = f2b(v.w);
  ((short4*)outb)[i] = o;
}

// in [R][C] f32 -> out [C][R] bf16
__global__ void transpose_f32_bf16(const float* __restrict__ in,
                                   short* __restrict__ out, int R, int C) {
  __shared__ float tile[32][33];
  int c0 = blockIdx.x * 32, r0 = blockIdx.y * 32;
  int tx = threadIdx.x, ty = threadIdx.y;  // 32 x 8
#pragma unroll
  for (int i = 0; i < 32; i += 8)
    tile[ty + i][tx] = in[(long)(r0 + ty + i) * C + c0 + tx];
  __syncthreads();
#pragma unroll
  for (int i = 0; i < 32; i += 8)
    out[(long)(c0 + ty + i) * R + r0 + tx] = f2b(tile[tx][ty + i]);
}

// ---------------- QKV GEMM: 256x256, liveness-derived pipeline ----------------

__global__ __launch_bounds__(512, 2) void gemm_qkv256(
    const short* __restrict__ A, const short* __restrict__ Bt,
    const float* __restrict__ bias,
    short* __restrict__ qh, short* __restrict__ kh, short* __restrict__ vT,
    int M, int N, int K) {
  __shared__ short As[2][256 * 64];
  __shared__ short Bs[2][256 * 64];
  const int t = threadIdx.x;
  const int wave = t >> 6, lane = t & 63;
  const int quad = lane >> 4, l15 = lane & 15;
  const int wm = wave >> 2, wn = wave & 3;
  const int m0 = blockIdx.y * 256, n0 = blockIdx.x * 256;

  f32x4 acc[8][4] = {};

  // staging addressing: thread t -> row sr = t>>3 within a 64-row round,
  // 16B chunk (t&7) pre-swizzled by row&7 (same proven pattern as r0).
  const int sr = t >> 3;               // 0..63
  const int sch = (t & 7) ^ (sr & 7);
  const int brA = sr + (sr & 32);      // {0-31,64-95}: per-wn first halves
  const short* aS = A + (long)(m0 + sr) * K + sch * 8;
  const short* bSa = Bt + (long)(n0 + brA) * K + sch * 8;
  const short* bSb = Bt + (long)(n0 + brA + 32) * K + sch * 8;
  const long K64 = (long)64 * K, K128 = (long)128 * K;
  const int dBa = brA * 64 + (t & 7) * 8;

  auto stgAa = [&](int tt) {  // A rows {0-63, 128-191}
    short* d = &As[tt & 1][0];
    const short* s = aS + (long)tt * 64;
    gl2lds16(d + t * 8, s);
    gl2lds16(d + 128 * 64 + t * 8, s + K128);
  };
  auto stgAb = [&](int tt) {  // A rows {64-127, 192-255}
    short* d = &As[tt & 1][0];
    const short* s = aS + (long)tt * 64 + K64;
    gl2lds16(d + 64 * 64 + t * 8, s);
    gl2lds16(d + 192 * 64 + t * 8, s + K128);
  };
  auto stgBa = [&](int tt) {  // B rows {0-31,64-95} + {128-159,192-223}
    short* d = &Bs[tt & 1][0];
    const short* s = bSa + (long)tt * 64;
    gl2lds16(d + dBa, s);
    gl2lds16(d + 128 * 64 + dBa, s + K128);
  };
  auto stgBb = [&](int tt) {  // B rows {32-63,96-127} + {160-191,224-255}
    short* d = &Bs[tt & 1][0];
    const short* s = bSb + (long)tt * 64;
    gl2lds16(d + 32 * 64 + dBa, s);
    gl2lds16(d + 160 * 64 + dBa, s + K128);
  };

  // fragment reads (proven conflict-free geometry)
  const int arow = wm * 128 + l15;
  const int brow = wn * 64 + l15;
  const int cx0 = (quad ^ (l15 & 7)) * 8;
  const int cx1 = ((4 + quad) ^ (l15 & 7)) * 8;
  bf16x8 af[4][2], bfr[2][2];

  auto LDA = [&](const short* Ab, int mh) {
#pragma unroll
    for (int i = 0; i < 4; ++i) {
      const short* p = Ab + (arow + mh * 64 + i * 16) * 64;
      af[i][0] = *(const bf16x8*)(p + cx0);
      af[i][1] = *(const bf16x8*)(p + cx1);
    }
  };
  auto LDB = [&](const short* Bb, int nh) {
#pragma unroll
    for (int j = 0; j < 2; ++j) {
      const short* p = Bb + (brow + nh * 32 + j * 16) * 64;
      bfr[j][0] = *(const bf16x8*)(p + cx0);
      bfr[j][1] = *(const bf16x8*)(p + cx1);
    }
  };
  auto MF = [&](int mh, int nh) {
#pragma unroll
    for (int s = 0; s < 2; ++s)
#pragma unroll
      for (int i = 0; i < 4; ++i)
#pragma unroll
        for (int j = 0; j < 2; ++j)
          acc[mh * 4 + i][nh * 2 + j] = __builtin_amdgcn_mfma_f32_16x16x32_bf16(
              af[i][s], bfr[j][s], acc[mh * 4 + i][nh * 2 + j], 0, 0, 0);
  };

  auto tileBody = [&](int tt, int mode) {  // mode 0=full 1=tail-1 2=last
    const short* Ab = &As[tt & 1][0];
    const short* Bb = &Bs[tt & 1][0];
    // ---- p0: (mh0, nh0)
    LDA(Ab, 0); LDB(Bb, 0);
    if (mode <= 1) stgBa(tt + 1);
    __builtin_amdgcn_s_barrier();
    asm volatile("s_waitcnt lgkmcnt(0)" ::: "memory");
    __builtin_amdgcn_sched_barrier(0);
    __builtin_amdgcn_s_setprio(1); MF(0, 0); __builtin_amdgcn_s_setprio(0);
    __builtin_amdgcn_s_barrier();
    // ---- p1: (mh0, nh1)
    LDB(Bb, 1);
    if (mode <= 1) stgAb(tt + 1);
    __builtin_amdgcn_s_barrier();
    asm volatile("s_waitcnt lgkmcnt(0)" ::: "memory");
    __builtin_amdgcn_sched_barrier(0);
    __builtin_amdgcn_s_setprio(1); MF(0, 1); __builtin_amdgcn_s_setprio(0);
    if (mode <= 1) asm volatile("s_waitcnt vmcnt(8)" ::: "memory");
    else asm volatile("s_waitcnt vmcnt(0)" ::: "memory");
    __builtin_amdgcn_s_barrier();
    // ---- p2: (mh1, nh1)
    LDA(Ab, 1);
    if (mode == 0) stgAa(tt + 2);
    __builtin_amdgcn_s_barrier();
    asm volatile("s_waitcnt lgkmcnt(0)" ::: "memory");
    __builtin_amdgcn_sched_barrier(0);
    __builtin_amdgcn_s_setprio(1); MF(1, 1); __builtin_amdgcn_s_setprio(0);
    __builtin_amdgcn_s_barrier();
    // ---- p3: (mh1, nh0)
    LDB(Bb, 0);
    if (mode == 0) stgBb(tt + 2);
    __builtin_amdgcn_s_barrier();
    asm volatile("s_waitcnt lgkmcnt(0)" ::: "memory");
    __builtin_amdgcn_sched_barrier(0);
    __builtin_amdgcn_s_setprio(1); MF(1, 0); __builtin_amdgcn_s_setprio(0);
    if (mode == 0) asm volatile("s_waitcnt vmcnt(6)" ::: "memory");
    else if (mode == 1) asm volatile("s_waitcnt vmcnt(2)" ::: "memory");
    __builtin_amdgcn_s_barrier();
  };

  // prologue: issue order = steady-state pattern shifted
  stgAa(0); stgBb(0); stgBa(0); stgAb(0); stgAa(1); stgBb(1);
  asm volatile("s_waitcnt vmcnt(6)" ::: "memory");
  __builtin_amdgcn_s_barrier();

  const int NT = K >> 6;  // 16
#pragma unroll 1
  for (int tt = 0; tt < NT - 2; ++tt) tileBody(tt, 0);
  tileBody(NT - 2, 1);
  tileBody(NT - 1, 2);

  // epilogue: scatter into q/k [bh][t][64] and vT [bh][64][1024]
  const int sec = n0 >> 10;
  const int b_ = m0 >> 10;
#pragma unroll
  for (int j = 0; j < 4; ++j) {
    int col = n0 + wn * 64 + j * 16 + l15;
    float bv = bias[col];
    int d = col & 1023, h = d >> 6, dh = d & 63;
    if (sec == 2) {
      long base = ((long)(b_ * 16 + h) * 64 + dh) * 1024;
#pragma unroll
      for (int i = 0; i < 8; ++i) {
        int tt0 = (m0 & 1023) + wm * 128 + i * 16 + quad * 4;
        short4 v;
        v.x = f2b(acc[i][j][0] + bv);
        v.y = f2b(acc[i][j][1] + bv);
        v.z = f2b(acc[i][j][2] + bv);
        v.w = f2b(acc[i][j][3] + bv);
        *(short4*)(vT + base + tt0) = v;
      }
    } else {
      short* dst = (sec == 0) ? qh : kh;
      long hbase = ((long)(b_ * 16 + h) * 1024) * 64 + dh;
#pragma unroll
      for (int i = 0; i < 8; ++i)
#pragma unroll
        for (int r = 0; r < 4; ++r) {
          int tt = (m0 & 1023) + wm * 128 + i * 16 + quad * 4 + r;
          dst[hbase + (long)tt * 64] = f2b(acc[i][j][r] + bv);
        }
    }
  }
}

// ---------------- proj GEMM: C[M,N] = A[M,K] * Bt[N,K]^T + bias ----------------

template <int EPI>
__global__ __launch_bounds__(256, 3) void gemm_bt(
    const short* __restrict__ A, const short* __restrict__ Bt,
    const float* __restrict__ bias, float* __restrict__ outF,
    short* __restrict__ qh, short* __restrict__ kh, short* __restrict__ vT,
    int M, int N, int K) {
  __shared__ short At[128 * 64];
  __shared__ short Bl[128 * 64];
  const int t = threadIdx.x;
  const int wave = t >> 6, lane = t & 63;
  const int quad = lane >> 4, l15 = lane & 15;
  const int wr = wave >> 1, wc = wave & 1;
  const int m0 = blockIdx.y * 128, n0 = blockIdx.x * 128;

  f32x4 acc[4][4] = {};

  const int srow = t >> 3;
  const int sch0 = t & 7;

  for (int k0 = 0; k0 < K; k0 += 64) {
    __syncthreads();
#pragma unroll
    for (int c = 0; c < 4; ++c) {
      int row = c * 32 + srow;
      int ch = sch0 ^ (row & 7);
      gl2lds16(At + (c * 256 + t) * 8, A + (long)(m0 + row) * K + k0 + ch * 8);
      gl2lds16(Bl + (c * 256 + t) * 8, Bt + (long)(n0 + row) * K + k0 + ch * 8);
    }
    asm volatile("s_waitcnt vmcnt(0)" ::: "memory");
    __syncthreads();

#pragma unroll
    for (int s = 0; s < 2; ++s) {
      const int cx = (s * 4 + quad) ^ (l15 & 7);
      bf16x8 af[4], bfr[4];
#pragma unroll
      for (int i = 0; i < 4; ++i)
        af[i] = *(const bf16x8*)(At + (wr * 64 + i * 16 + l15) * 64 + cx * 8);
#pragma unroll
      for (int j = 0; j < 4; ++j)
        bfr[j] = *(const bf16x8*)(Bl + (wc * 64 + j * 16 + l15) * 64 + cx * 8);
#pragma unroll
      for (int i = 0; i < 4; ++i)
#pragma unroll
        for (int j = 0; j < 4; ++j)
          acc[i][j] = __builtin_amdgcn_mfma_f32_16x16x32_bf16(af[i], bfr[j],
                                                              acc[i][j], 0, 0, 0);
    }
  }

  if (EPI == 1) {
#pragma unroll
    for (int j = 0; j < 4; ++j) {
      int col = n0 + wc * 64 + j * 16 + l15;
      float bv = bias[col];
#pragma unroll
      for (int i = 0; i < 4; ++i)
#pragma unroll
        for (int r = 0; r < 4; ++r) {
          int row = m0 + wr * 64 + i * 16 + quad * 4 + r;
          outF[(long)row * N + col] = acc[i][j][r] + bv;
        }
    }
  }
}

// ---------------- fused flash attention (r0-exact) ----------------

__global__ __launch_bounds__(256, 2) void attn_kernel(
    const short* __restrict__ qh, const short* __restrict__ kh,
    const short* __restrict__ vT, short* __restrict__ attout) {
  __shared__ short Kb[2][64 * 64];
  __shared__ short Vb[2][64 * 64];
  __shared__ short P_lds[4][16][64];  // swizzled chunks: ch' = ch ^ (row&7)
  const int p = blockIdx.x;  // 0..3
  const int bh = blockIdx.y;
  const int t = threadIdx.x;
  const int wave = t >> 6, lane = t & 63, quad = lane >> 4, l15 = lane & 15;
  const short* q_head = qh + (long)bh * 1024 * 64;
  const short* k_head = kh + (long)bh * 1024 * 64;
  const short* v_head = vT + (long)bh * 64 * 1024;
  const int b_ = bh >> 4, h_ = bh & 15;
  const float sl = 0.125f * 1.44269504089f;  // scale * log2(e)

  const int qt[4] = {p, 7 - p, 8 + p, 15 - p};  // ascending

  auto stage = [&](int kt, int buf) {
    const int kk0 = kt * 64;
#pragma unroll
    for (int i = 0; i < 2; ++i) {
      int s = i * 256 + t;
      int row = s >> 3, cg = (s & 7) ^ (row & 7);
      gl2lds16(&Kb[buf][s * 8], k_head + (kk0 + row) * 64 + cg * 8);
    }
#pragma unroll
    for (int i = 0; i < 2; ++i) {
      int s = i * 256 + t;
      int row = s >> 3, cg = (s & 7) ^ (row & 7);
      gl2lds16(&Vb[buf][s * 8], v_head + row * 1024 + kk0 + cg * 8);
    }
  };

  bf16x8 qf[4][2];
#pragma unroll
  for (int i = 0; i < 4; ++i) {
    int qb = qt[i] * 64 + wave * 16;
#pragma unroll
    for (int s = 0; s < 2; ++s)
      qf[i][s] = *(const bf16x8*)(q_head + (qb + l15) * 64 + s * 32 + quad * 8);
  }

  float l[4][4] = {};
  f32x4 o[4][4] = {};

  stage(0, 0);
  __syncthreads();

  const int nkt = qt[3] + 1;  // 16 - p

#pragma unroll 1
  for (int kt = 0; kt < nkt; ++kt) {
    const int buf = kt & 1;
    const short* Kt = Kb[buf];
    const short* Vt = Vb[buf];

    // preload K and V fragments once; shared by all active q-tiles
    bf16x8 kfr[4][2], vfr[4][2];
#pragma unroll
    for (int jj = 0; jj < 4; ++jj) {
      int row = jj * 16 + l15;
#pragma unroll
      for (int s = 0; s < 2; ++s) {
        int off = ((s * 4 + quad) ^ (row & 7)) * 8;
        kfr[jj][s] = *(const bf16x8*)(Kt + row * 64 + off);
        vfr[jj][s] = *(const bf16x8*)(Vt + row * 64 + off);
      }
    }

    if (kt + 1 < nkt) stage(kt + 1, buf ^ 1);  // overlaps with compute below

#pragma unroll
    for (int i = 0; i < 4; ++i) {
      if (kt <= qt[i]) {
        f32x4 s4[4] = {};
#pragma unroll
        for (int jj = 0; jj < 4; ++jj) {
          s4[jj] = __builtin_amdgcn_mfma_f32_16x16x32_bf16(qf[i][0], kfr[jj][0],
                                                           s4[jj], 0, 0, 0);
          s4[jj] = __builtin_amdgcn_mfma_f32_16x16x32_bf16(qf[i][1], kfr[jj][1],
                                                           s4[jj], 0, 0, 0);
        }
        const bool diag = (kt == qt[i]);
        const int qb = qt[i] * 64 + wave * 16;
#pragma unroll
        for (int jj = 0; jj < 4; ++jj) {
          int key = kt * 64 + jj * 16 + l15;
          int ch = jj * 2 + (l15 >> 3), co = l15 & 7;
#pragma unroll
          for (int r = 0; r < 4; ++r) {
            int row = quad * 4 + r;
            float sv = s4[jj][r] * sl;
            if (diag && key > qb + row) sv = -1e30f;
            float e = __builtin_amdgcn_exp2f(sv);
            l[i][r] += e;
            P_lds[wave][row][(ch ^ (row & 7)) * 8 + co] = f2b(e);
          }
        }
        asm volatile("s_waitcnt lgkmcnt(0)" ::: "memory");
        bf16x8 pf[2];
#pragma unroll
        for (int s = 0; s < 2; ++s)
          pf[s] =
              *(const bf16x8*)(&P_lds[wave][l15][((s * 4 + quad) ^ (l15 & 7)) * 8]);
#pragma unroll
        for (int dj = 0; dj < 4; ++dj) {
          o[i][dj] = __builtin_amdgcn_mfma_f32_16x16x32_bf16(pf[0], vfr[dj][0],
                                                             o[i][dj], 0, 0, 0);
          o[i][dj] = __builtin_amdgcn_mfma_f32_16x16x32_bf16(pf[1], vfr[dj][1],
                                                             o[i][dj], 0, 0, 0);
        }
      }
    }
    __syncthreads();  // releases buf for re-stage; drains prefetch vmcnt
  }

  // deferred l reductions
#pragma unroll
  for (int off = 1; off < 16; off <<= 1)
#pragma unroll
    for (int i = 0; i < 4; ++i)
#pragma unroll
      for (int r = 0; r < 4; ++r) l[i][r] += __shfl_xor(l[i][r], off);

  // epilogue: per tile, C-layout -> rows via P_lds, then cached 16B stores.
  const int erow = lane >> 3, ech = lane & 7;
#pragma unroll
  for (int i = 0; i < 4; ++i) {
    float inv[4];
#pragma unroll
    for (int r = 0; r < 4; ++r) inv[r] = __builtin_amdgcn_rcpf(l[i][r]);
    const int qb = qt[i] * 64 + wave * 16;
#pragma unroll
    for (int dj = 0; dj < 4; ++dj) {
      int ch = dj * 2 + (l15 >> 3), co = l15 & 7;
#pragma unroll
      for (int r = 0; r < 4; ++r) {
        int row = quad * 4 + r;
        P_lds[wave][row][(ch ^ (row & 7)) * 8 + co] = f2b(o[i][dj][r] * inv[r]);
      }
    }
    asm volatile("s_waitcnt lgkmcnt(0)" ::: "memory");
#pragma unroll
    for (int pass = 0; pass < 2; ++pass) {
      int row = pass * 8 + erow;
      bf16x8 v = *(const bf16x8*)(&P_lds[wave][row][(ech ^ (row & 7)) * 8]);
      long g = (long)b_ * 1024 + qb + row;
      *(bf16x8*)(attout + g * 1024 + h_ * 64 + ech * 8) = v;
    }
    asm volatile("s_waitcnt lgkmcnt(0)" ::: "memory");  // reads before next writes
  }
}

// ---------------- launch ----------------

extern "C" void kernel_launch(void* const* d_in, const int* in_sizes, int n_in,
                              void* d_out, int out_size, void* d_ws,
                              size_t ws_size, hipStream_t stream) {
  const float* x = (const float*)d_in[0];
  const float* W_attn = (const float*)d_in[2];
  const float* b_attn = (const float*)d_in[3];
  const float* W_proj = (const float*)d_in[4];
  const float* b_proj = (const float*)d_in[5];
  float* out = (float*)d_out;

  char* ws = (char*)d_ws;
  const size_t MB = 1u << 20;
  short* xb = (short*)(ws);              // 16 MB [0,16)
  short* WaT = (short*)(ws + 16 * MB);   // 6 MB  [16,22)
  short* WpT = (short*)(ws + 22 * MB);   // 2 MB  [22,24)
  short* qh = (short*)(ws + 24 * MB);    // 16 MB [24,40)
  short* kh = (short*)(ws + 40 * MB);    // 16 MB [40,56)
  short* vT = (short*)(ws + 56 * MB);    // 16 MB [56,72)
  short* attout = xb;                    // reuse x-bf16 region

  f32_to_bf16_vec<<<8192, 256, 0, stream>>>(x, xb, 2097152);
  transpose_f32_bf16<<<dim3(3072 / 32, 1024 / 32), dim3(32, 8), 0, stream>>>(
      W_attn, WaT, 1024, 3072);
  transpose_f32_bf16<<<dim3(1024 / 32, 1024 / 32), dim3(32, 8), 0, stream>>>(
      W_proj, WpT, 1024, 1024);
  gemm_qkv256<<<dim3(3072 / 256, 8192 / 256), 512, 0, stream>>>(
      xb, WaT, b_attn, qh, kh, vT, 8192, 3072, 1024);
  attn_kernel<<<dim3(4, 128), 256, 0, stream>>>(qh, kh, vT, attout);
  gemm_bt<1><<<dim3(1024 / 128, 8192 / 128), 256, 0, stream>>>(
      attout, WpT, b_proj, out, nullptr, nullptr, nullptr, 8192, 1024, 1024);
}

// Round 5
// 230.150 us; speedup vs baseline: 1.0953x; 1.0953x over previous
//
#include <hip/hip_runtime.h>
#include <cstdint>

// B=8, T=1024, D=1024, H=16, hd=64
// prep (bf16 convert + weight transpose) -> QKV GEMM (proven 128^2 2-phase)
// -> fused flash attention -> proj GEMM (128^2 2-phase).
//
// r5: GEMMs are r0-exact (59.5us QKV, 866TF, 0 conflicts; three 256^2
// deep-pipeline ports all regressed 79-98us -- abandoned).
// attn v7: swapped QK^T (mfma(K,Q) -> lane holds S^T: one q-row (l15),
// keys jj*16+quad*4+r) + key-permutation pi(slot s*32+quad*8+4cs+r) =
// (2s+cs)*16+quad*4+r applied to BOTH the P A-operand and the V B-operand.
// pi preserves quad => P fragments are an in-lane repack of the lane's own
// 16 exp values: NO P_lds round-trip, no lgkmcnt serialization, no ds_writes
// in the softmax path. V fragments use paired ds_read_b64 at the permuted
// chunks (<=2-way bank aliasing = free). l becomes 1 float/lane (in-lane
// row-sum + 2 shfl_xor at the end); epilogue inv via one shfl per row.

typedef __attribute__((ext_vector_type(8))) short bf16x8;
typedef __attribute__((ext_vector_type(4))) float f32x4;

__device__ __forceinline__ short f2b(float x) {
  unsigned u = __builtin_bit_cast(unsigned, x);
  u += 0x7fffu + ((u >> 16) & 1u);
  return (short)(u >> 16);
}

__device__ __forceinline__ void gl2lds16(short* l, const short* g) {
  __builtin_amdgcn_global_load_lds(
      (const __attribute__((address_space(1))) void*)g,
      (__attribute__((address_space(3))) void*)l, 16, 0, 0);
}

// ---------------- prep kernels ----------------

__global__ void f32_to_bf16_vec(const float* __restrict__ in,
                                short* __restrict__ outb, int n4) {
  int i = blockIdx.x * 256 + threadIdx.x;
  if (i >= n4) return;
  float4 v = ((const float4*)in)[i];
  short4 o;
  o.x = f2b(v.x); o.y = f2b(v.y); o.z = f2b(v.z); o.w = f2b(v.w);
  ((short4*)outb)[i] = o;
}

// in [R][C] f32 -> out [C][R] bf16
__global__ void transpose_f32_bf16(const float* __restrict__ in,
                                   short* __restrict__ out, int R, int C) {
  __shared__ float tile[32][33];
  int c0 = blockIdx.x * 32, r0 = blockIdx.y * 32;
  int tx = threadIdx.x, ty = threadIdx.y;  // 32 x 8
#pragma unroll
  for (int i = 0; i < 32; i += 8)
    tile[ty + i][tx] = in[(long)(r0 + ty + i) * C + c0 + tx];
  __syncthreads();
#pragma unroll
  for (int i = 0; i < 32; i += 8)
    out[(long)(c0 + ty + i) * R + r0 + tx] = f2b(tile[tx][ty + i]);
}

// ---------------- GEMM: C[M,N] = A[M,K] * Bt[N,K]^T + bias ----------------

template <int EPI>
__global__ __launch_bounds__(256, 3) void gemm_bt(
    const short* __restrict__ A, const short* __restrict__ Bt,
    const float* __restrict__ bias, float* __restrict__ outF,
    short* __restrict__ qh, short* __restrict__ kh, short* __restrict__ vT,
    int M, int N, int K) {
  __shared__ short At[128 * 64];
  __shared__ short Bl[128 * 64];
  const int t = threadIdx.x;
  const int wave = t >> 6, lane = t & 63;
  const int quad = lane >> 4, l15 = lane & 15;
  const int wr = wave >> 1, wc = wave & 1;
  const int m0 = blockIdx.y * 128, n0 = blockIdx.x * 128;

  f32x4 acc[4][4] = {};

  const int srow = t >> 3;
  const int sch0 = t & 7;

  for (int k0 = 0; k0 < K; k0 += 64) {
    __syncthreads();
#pragma unroll
    for (int c = 0; c < 4; ++c) {
      int row = c * 32 + srow;
      int ch = sch0 ^ (row & 7);
      gl2lds16(At + (c * 256 + t) * 8, A + (long)(m0 + row) * K + k0 + ch * 8);
      gl2lds16(Bl + (c * 256 + t) * 8, Bt + (long)(n0 + row) * K + k0 + ch * 8);
    }
    asm volatile("s_waitcnt vmcnt(0)" ::: "memory");
    __syncthreads();

#pragma unroll
    for (int s = 0; s < 2; ++s) {
      const int cx = (s * 4 + quad) ^ (l15 & 7);
      bf16x8 af[4], bfr[4];
#pragma unroll
      for (int i = 0; i < 4; ++i)
        af[i] = *(const bf16x8*)(At + (wr * 64 + i * 16 + l15) * 64 + cx * 8);
#pragma unroll
      for (int j = 0; j < 4; ++j)
        bfr[j] = *(const bf16x8*)(Bl + (wc * 64 + j * 16 + l15) * 64 + cx * 8);
#pragma unroll
      for (int i = 0; i < 4; ++i)
#pragma unroll
        for (int j = 0; j < 4; ++j)
          acc[i][j] = __builtin_amdgcn_mfma_f32_16x16x32_bf16(af[i], bfr[j],
                                                              acc[i][j], 0, 0, 0);
    }
  }

  if (EPI == 1) {
#pragma unroll
    for (int j = 0; j < 4; ++j) {
      int col = n0 + wc * 64 + j * 16 + l15;
      float bv = bias[col];
#pragma unroll
      for (int i = 0; i < 4; ++i)
#pragma unroll
        for (int r = 0; r < 4; ++r) {
          int row = m0 + wr * 64 + i * 16 + quad * 4 + r;
          outF[(long)row * N + col] = acc[i][j][r] + bv;
        }
    }
  } else {
    const int sec = n0 >> 10;
    const int b = m0 >> 10;
#pragma unroll
    for (int j = 0; j < 4; ++j) {
      int col = n0 + wc * 64 + j * 16 + l15;
      float bv = bias[col];
      int d = col & 1023, h = d >> 6, dh = d & 63;
      if (sec == 2) {
        long base = ((long)(b * 16 + h) * 64 + dh) * 1024;
#pragma unroll
        for (int i = 0; i < 4; ++i) {
          int tt0 = (m0 & 1023) + wr * 64 + i * 16 + quad * 4;
          short4 v;
          v.x = f2b(acc[i][j][0] + bv);
          v.y = f2b(acc[i][j][1] + bv);
          v.z = f2b(acc[i][j][2] + bv);
          v.w = f2b(acc[i][j][3] + bv);
          *(short4*)(vT + base + tt0) = v;
        }
      } else {
        short* dst = (sec == 0) ? qh : kh;
        long hbase = ((long)(b * 16 + h) * 1024) * 64 + dh;
#pragma unroll
        for (int i = 0; i < 4; ++i)
#pragma unroll
          for (int r = 0; r < 4; ++r) {
            int tt = (m0 & 1023) + wr * 64 + i * 16 + quad * 4 + r;
            dst[hbase + (long)tt * 64] = f2b(acc[i][j][r] + bv);
          }
      }
    }
  }
}

// ---------------- fused flash attention ----------------
// grid (4, 128). Block owns q-tiles {p, 7-p, 8+p, 15-p} (ascending, balanced:
// 34 active tile-iters for every p). One k-loop to qt[3]; stage each K/V tile
// once, preload K+V fragments once, apply to all active tiles.
// Softmax fully in-register (swapped QK + key permutation, see header).
// P_lds retained for the output epilogue transpose only.

__global__ __launch_bounds__(256, 2) void attn_kernel(
    const short* __restrict__ qh, const short* __restrict__ kh,
    const short* __restrict__ vT, short* __restrict__ attout) {
  __shared__ short Kb[2][64 * 64];
  __shared__ short Vb[2][64 * 64];
  __shared__ short P_lds[4][16][64];  // epilogue staging only
  const int p = blockIdx.x;  // 0..3
  const int bh = blockIdx.y;
  const int t = threadIdx.x;
  const int wave = t >> 6, lane = t & 63, quad = lane >> 4, l15 = lane & 15;
  const short* q_head = qh + (long)bh * 1024 * 64;
  const short* k_head = kh + (long)bh * 1024 * 64;
  const short* v_head = vT + (long)bh * 64 * 1024;
  const int b_ = bh >> 4, h_ = bh & 15;
  const float sl = 0.125f * 1.44269504089f;  // scale * log2(e)

  const int qt[4] = {p, 7 - p, 8 + p, 15 - p};  // ascending

  auto stage = [&](int kt, int buf) {
    const int kk0 = kt * 64;
#pragma unroll
    for (int i = 0; i < 2; ++i) {
      int s = i * 256 + t;
      int row = s >> 3, cg = (s & 7) ^ (row & 7);
      gl2lds16(&Kb[buf][s * 8], k_head + (kk0 + row) * 64 + cg * 8);
    }
#pragma unroll
    for (int i = 0; i < 2; ++i) {
      int s = i * 256 + t;
      int row = s >> 3, cg = (s & 7) ^ (row & 7);
      gl2lds16(&Vb[buf][s * 8], v_head + row * 1024 + kk0 + cg * 8);
    }
  };

  bf16x8 qf[4][2];
#pragma unroll
  for (int i = 0; i < 4; ++i) {
    int qb = qt[i] * 64 + wave * 16;
#pragma unroll
    for (int s = 0; s < 2; ++s)
      qf[i][s] = *(const bf16x8*)(q_head + (qb + l15) * 64 + s * 32 + quad * 8);
  }

  float l[4] = {};
  f32x4 o[4][4] = {};

  stage(0, 0);
  __syncthreads();

  const int nkt = qt[3] + 1;  // 16 - p

#pragma unroll 1
  for (int kt = 0; kt < nkt; ++kt) {
    const int buf = kt & 1;
    const short* Kt = Kb[buf];
    const short* Vt = Vb[buf];

    // K fragments: identity slot map (row = key, chunk = s*4+quad, swizzled)
    bf16x8 kfr[4][2];
#pragma unroll
    for (int jj = 0; jj < 4; ++jj) {
      int row = jj * 16 + l15;
#pragma unroll
      for (int s = 0; s < 2; ++s) {
        int off = ((s * 4 + quad) ^ (row & 7)) * 8;
        kfr[jj][s] = *(const bf16x8*)(Kt + row * 64 + off);
      }
    }
    // V fragments: permuted key map pi -> two 8B segments per fragment.
    // slot (s,quad,4cs+r) -> key (2s+cs)*16 + quad*4 + r
    // chunk = (2s+cs)*2 + (quad>>1), intra-chunk short offset (quad&1)*4 + r
    bf16x8 vfr[4][2];
    {
      const int qh2 = quad >> 1, ql4 = (quad & 1) * 4;
#pragma unroll
      for (int dj = 0; dj < 4; ++dj) {
        int row = dj * 16 + l15, r7 = row & 7;
        const short* vr = Vt + row * 64;
        short4 a0 = *(const short4*)(vr + ((qh2 ^ r7) * 8) + ql4);
        short4 a1 = *(const short4*)(vr + (((2 + qh2) ^ r7) * 8) + ql4);
        short4 a2 = *(const short4*)(vr + (((4 + qh2) ^ r7) * 8) + ql4);
        short4 a3 = *(const short4*)(vr + (((6 + qh2) ^ r7) * 8) + ql4);
        bf16x8 v0, v1;
        v0[0] = a0.x; v0[1] = a0.y; v0[2] = a0.z; v0[3] = a0.w;
        v0[4] = a1.x; v0[5] = a1.y; v0[6] = a1.z; v0[7] = a1.w;
        v1[0] = a2.x; v1[1] = a2.y; v1[2] = a2.z; v1[3] = a2.w;
        v1[4] = a3.x; v1[5] = a3.y; v1[6] = a3.z; v1[7] = a3.w;
        vfr[dj][0] = v0;
        vfr[dj][1] = v1;
      }
    }

    if (kt + 1 < nkt) stage(kt + 1, buf ^ 1);  // overlaps with compute below

#pragma unroll
    for (int i = 0; i < 4; ++i) {
      if (kt <= qt[i]) {
        // swapped QK: S^T; lane (l15,quad) holds S[q=qg][key jj*16+quad*4+r]
        f32x4 s4[4] = {};
#pragma unroll
        for (int jj = 0; jj < 4; ++jj) {
          s4[jj] = __builtin_amdgcn_mfma_f32_16x16x32_bf16(kfr[jj][0], qf[i][0],
                                                           s4[jj], 0, 0, 0);
          s4[jj] = __builtin_amdgcn_mfma_f32_16x16x32_bf16(kfr[jj][1], qf[i][1],
                                                           s4[jj], 0, 0, 0);
        }
        const bool diag = (kt == qt[i]);
        const int qg = qt[i] * 64 + wave * 16 + l15;  // this lane's q row
        bf16x8 pf0, pf1;
        float ls = 0.f;
#pragma unroll
        for (int jj = 0; jj < 4; ++jj) {
          const int kbase = kt * 64 + jj * 16 + quad * 4;
#pragma unroll
          for (int r = 0; r < 4; ++r) {
            float sv = s4[jj][r] * sl;
            if (diag && (kbase + r) > qg) sv = -1e30f;
            float e = __builtin_amdgcn_exp2f(sv);
            ls += e;
            short bv = f2b(e);
            if (jj < 2) pf0[(jj & 1) * 4 + r] = bv;
            else pf1[(jj & 1) * 4 + r] = bv;
          }
        }
        l[i] += ls;
#pragma unroll
        for (int dj = 0; dj < 4; ++dj) {
          o[i][dj] = __builtin_amdgcn_mfma_f32_16x16x32_bf16(pf0, vfr[dj][0],
                                                             o[i][dj], 0, 0, 0);
          o[i][dj] = __builtin_amdgcn_mfma_f32_16x16x32_bf16(pf1, vfr[dj][1],
                                                             o[i][dj], 0, 0, 0);
        }
      }
    }
    __syncthreads();  // releases buf for re-stage; drains prefetch vmcnt
  }

  // deferred l reductions: sum partial row-sums across the 4 quads
#pragma unroll
  for (int i = 0; i < 4; ++i) {
    l[i] += __shfl_xor(l[i], 16);
    l[i] += __shfl_xor(l[i], 32);
  }

  // epilogue: per tile, C-layout -> rows via P_lds, then cached 16B stores.
  const int erow = lane >> 3, ech = lane & 7;
#pragma unroll
  for (int i = 0; i < 4; ++i) {
    float inv[4];
#pragma unroll
    for (int r = 0; r < 4; ++r) {
      float lr = __shfl(l[i], quad * 4 + r);  // row-sum lives in lane l15=row
      inv[r] = __builtin_amdgcn_rcpf(lr);
    }
    const int qb = qt[i] * 64 + wave * 16;
#pragma unroll
    for (int dj = 0; dj < 4; ++dj) {
      int ch = dj * 2 + (l15 >> 3), co = l15 & 7;
#pragma unroll
      for (int r = 0; r < 4; ++r) {
        int row = quad * 4 + r;
        P_lds[wave][row][(ch ^ (row & 7)) * 8 + co] = f2b(o[i][dj][r] * inv[r]);
      }
    }
    asm volatile("s_waitcnt lgkmcnt(0)" ::: "memory");
#pragma unroll
    for (int pass = 0; pass < 2; ++pass) {
      int row = pass * 8 + erow;
      bf16x8 v = *(const bf16x8*)(&P_lds[wave][row][(ech ^ (row & 7)) * 8]);
      long g = (long)b_ * 1024 + qb + row;
      *(bf16x8*)(attout + g * 1024 + h_ * 64 + ech * 8) = v;
    }
    asm volatile("s_waitcnt lgkmcnt(0)" ::: "memory");  // reads before next writes
  }
}

// ---------------- launch ----------------

extern "C" void kernel_launch(void* const* d_in, const int* in_sizes, int n_in,
                              void* d_out, int out_size, void* d_ws,
                              size_t ws_size, hipStream_t stream) {
  const float* x = (const float*)d_in[0];
  const float* W_attn = (const float*)d_in[2];
  const float* b_attn = (const float*)d_in[3];
  const float* W_proj = (const float*)d_in[4];
  const float* b_proj = (const float*)d_in[5];
  float* out = (float*)d_out;

  char* ws = (char*)d_ws;
  const size_t MB = 1u << 20;
  short* xb = (short*)(ws);              // 16 MB [0,16)
  short* WaT = (short*)(ws + 16 * MB);   // 6 MB  [16,22)
  short* WpT = (short*)(ws + 22 * MB);   // 2 MB  [22,24)
  short* qh = (short*)(ws + 24 * MB);    // 16 MB [24,40)
  short* kh = (short*)(ws + 40 * MB);    // 16 MB [40,56)
  short* vT = (short*)(ws + 56 * MB);    // 16 MB [56,72)
  short* attout = xb;                    // reuse x-bf16 region

  f32_to_bf16_vec<<<8192, 256, 0, stream>>>(x, xb, 2097152);
  transpose_f32_bf16<<<dim3(3072 / 32, 1024 / 32), dim3(32, 8), 0, stream>>>(
      W_attn, WaT, 1024, 3072);
  transpose_f32_bf16<<<dim3(1024 / 32, 1024 / 32), dim3(32, 8), 0, stream>>>(
      W_proj, WpT, 1024, 1024);
  gemm_bt<0><<<dim3(3072 / 128, 8192 / 128), 256, 0, stream>>>(
      xb, WaT, b_attn, nullptr, qh, kh, vT, 8192, 3072, 1024);
  attn_kernel<<<dim3(4, 128), 256, 0, stream>>>(qh, kh, vT, attout);
  gemm_bt<1><<<dim3(1024 / 128, 8192 / 128), 256, 0, stream>>>(
      attout, WpT, b_proj, out, nullptr, nullptr, nullptr, 8192, 1024, 1024);
}

// Round 6
// 201.763 us; speedup vs baseline: 1.2494x; 1.1407x over previous
//
#include <hip/hip_runtime.h>
#include <cstdint>

// B=8, T=1024, D=1024, H=16, hd=64
// prep (fused: bf16 convert + 2 weight transposes) -> QKV GEMM (proven 128^2
// 2-phase) -> fused flash attention (swapped-QK in-register softmax) ->
// proj GEMM (128^2).
//
// r6 deltas vs r5 (all attn/prep; GEMM core untouched):
//  - q pre-scaled by 0.125*log2e in QKV epilogue -> no per-score mul in attn
//  - diag branch hoisted (uniform) -> no cndmask on 30/34 tile-iters
//  - P pack via v_cvt_pk_bf16_f32 (8 instr vs 48)
//  - vT stored sigma-permuted (col' = (a>>1)*32+q*8+(a&1)*4+r for key
//    k=16a+4q+r) so V fragments are identity b128 reads (same as K);
//    consistent with P-operand permutation pi (validated in r5)
//  - attn grid (128,4): same-bh blocks -> ids differ by 128 = 0 mod 8 ->
//    same XCD -> K/V L2 co-location
//  - prep fused into one kernel (6 -> 4 launches)

typedef __attribute__((ext_vector_type(8))) short bf16x8;
typedef __attribute__((ext_vector_type(4))) float f32x4;

__device__ __forceinline__ short f2b(float x) {
  unsigned u = __builtin_bit_cast(unsigned, x);
  u += 0x7fffu + ((u >> 16) & 1u);
  return (short)(u >> 16);
}

__device__ __forceinline__ unsigned cvtpk(float lo, float hi) {
  unsigned d;
  asm("v_cvt_pk_bf16_f32 %0, %1, %2" : "=v"(d) : "v"(lo), "v"(hi));
  return d;
}

__device__ __forceinline__ void gl2lds16(short* l, const short* g) {
  __builtin_amdgcn_global_load_lds(
      (const __attribute__((address_space(1))) void*)g,
      (__attribute__((address_space(3))) void*)l, 16, 0, 0);
}

// ---------------- fused prep ----------------
// blocks [0,8192): f32->bf16 convert of x (float4/short4 vectorized)
// blocks [8192,11264): transpose W_attn [1024][3072] -> [3072][1024] bf16
// blocks [11264,12288): transpose W_proj [1024][1024] -> [1024][1024] bf16

__global__ void prep_fused(const float* __restrict__ x, short* __restrict__ xb,
                           const float* __restrict__ Wa, short* __restrict__ WaT,
                           const float* __restrict__ Wp, short* __restrict__ WpT) {
  __shared__ float tile[32][33];
  const int bid = blockIdx.x;
  const int t = threadIdx.x;
  if (bid < 8192) {
    int i = bid * 256 + t;
    float4 v = ((const float4*)x)[i];
    short4 o;
    o.x = f2b(v.x); o.y = f2b(v.y); o.z = f2b(v.z); o.w = f2b(v.w);
    ((short4*)xb)[i] = o;
    return;
  }
  const float* in;
  short* out;
  int C, bx, by;
  if (bid < 11264) {
    int id = bid - 8192;
    in = Wa; out = WaT; C = 3072; bx = id % 96; by = id / 96;
  } else {
    int id = bid - 11264;
    in = Wp; out = WpT; C = 1024; bx = id % 32; by = id / 32;
  }
  const int R = 1024;
  int c0 = bx * 32, r0 = by * 32;
  int tx = t & 31, ty = t >> 5;  // 32 x 8
#pragma unroll
  for (int i = 0; i < 32; i += 8)
    tile[ty + i][tx] = in[(long)(r0 + ty + i) * C + c0 + tx];
  __syncthreads();
#pragma unroll
  for (int i = 0; i < 32; i += 8)
    out[(long)(c0 + ty + i) * R + r0 + tx] = f2b(tile[tx][ty + i]);
}

// ---------------- GEMM: C[M,N] = A[M,K] * Bt[N,K]^T + bias ----------------

template <int EPI>
__global__ __launch_bounds__(256, 3) void gemm_bt(
    const short* __restrict__ A, const short* __restrict__ Bt,
    const float* __restrict__ bias, float* __restrict__ outF,
    short* __restrict__ qh, short* __restrict__ kh, short* __restrict__ vT,
    int M, int N, int K) {
  __shared__ short At[128 * 64];
  __shared__ short Bl[128 * 64];
  const int t = threadIdx.x;
  const int wave = t >> 6, lane = t & 63;
  const int quad = lane >> 4, l15 = lane & 15;
  const int wr = wave >> 1, wc = wave & 1;
  const int m0 = blockIdx.y * 128, n0 = blockIdx.x * 128;

  f32x4 acc[4][4] = {};

  const int srow = t >> 3;
  const int sch0 = t & 7;

  for (int k0 = 0; k0 < K; k0 += 64) {
    __syncthreads();
#pragma unroll
    for (int c = 0; c < 4; ++c) {
      int row = c * 32 + srow;
      int ch = sch0 ^ (row & 7);
      gl2lds16(At + (c * 256 + t) * 8, A + (long)(m0 + row) * K + k0 + ch * 8);
      gl2lds16(Bl + (c * 256 + t) * 8, Bt + (long)(n0 + row) * K + k0 + ch * 8);
    }
    asm volatile("s_waitcnt vmcnt(0)" ::: "memory");
    __syncthreads();

#pragma unroll
    for (int s = 0; s < 2; ++s) {
      const int cx = (s * 4 + quad) ^ (l15 & 7);
      bf16x8 af[4], bfr[4];
#pragma unroll
      for (int i = 0; i < 4; ++i)
        af[i] = *(const bf16x8*)(At + (wr * 64 + i * 16 + l15) * 64 + cx * 8);
#pragma unroll
      for (int j = 0; j < 4; ++j)
        bfr[j] = *(const bf16x8*)(Bl + (wc * 64 + j * 16 + l15) * 64 + cx * 8);
#pragma unroll
      for (int i = 0; i < 4; ++i)
#pragma unroll
        for (int j = 0; j < 4; ++j)
          acc[i][j] = __builtin_amdgcn_mfma_f32_16x16x32_bf16(af[i], bfr[j],
                                                              acc[i][j], 0, 0, 0);
    }
  }

  if (EPI == 1) {
#pragma unroll
    for (int j = 0; j < 4; ++j) {
      int col = n0 + wc * 64 + j * 16 + l15;
      float bv = bias[col];
#pragma unroll
      for (int i = 0; i < 4; ++i)
#pragma unroll
        for (int r = 0; r < 4; ++r) {
          int row = m0 + wr * 64 + i * 16 + quad * 4 + r;
          outF[(long)row * N + col] = acc[i][j][r] + bv;
        }
    }
  } else {
    const int sec = n0 >> 10;
    const int b = m0 >> 10;
    // q pre-scale: fold softmax scale * log2(e) into q (exact same math as
    // multiplying S later; one bf16 rounding either way).
    const float sc = (sec == 0) ? (0.125f * 1.44269504089f) : 1.0f;
#pragma unroll
    for (int j = 0; j < 4; ++j) {
      int col = n0 + wc * 64 + j * 16 + l15;
      float bv = bias[col];
      int d = col & 1023, h = d >> 6, dh = d & 63;
      if (sec == 2) {
        long base = ((long)(b * 16 + h) * 64 + dh) * 1024;
#pragma unroll
        for (int i = 0; i < 4; ++i) {
          // sigma-permuted key layout: k=16i+4*quad+r -> col'
          int tt0 = (m0 & 1023) + wr * 64 + (i >> 1) * 32 + quad * 8 + (i & 1) * 4;
          short4 v;
          v.x = f2b(acc[i][j][0] + bv);
          v.y = f2b(acc[i][j][1] + bv);
          v.z = f2b(acc[i][j][2] + bv);
          v.w = f2b(acc[i][j][3] + bv);
          *(short4*)(vT + base + tt0) = v;
        }
      } else {
        short* dst = (sec == 0) ? qh : kh;
        long hbase = ((long)(b * 16 + h) * 1024) * 64 + dh;
#pragma unroll
        for (int i = 0; i < 4; ++i)
#pragma unroll
          for (int r = 0; r < 4; ++r) {
            int tt = (m0 & 1023) + wr * 64 + i * 16 + quad * 4 + r;
            dst[hbase + (long)tt * 64] = f2b((acc[i][j][r] + bv) * sc);
          }
      }
    }
  }
}

// ---------------- fused flash attention ----------------
// grid (128, 4): x = bh (same-bh p-siblings land on the same XCD), y = p.
// Block owns q-tiles {p, 7-p, 8+p, 15-p}. Swapped QK (mfma(K,Q)): lane
// (l15,quad) holds S^T for q-row l15, keys jj*16+quad*4+r. P stays in
// registers (pi-permuted pack, cvt_pk); V stored sigma-permuted in vT so
// V fragments are identity b128 reads. P_lds: epilogue transpose only.

__global__ __launch_bounds__(256, 2) void attn_kernel(
    const short* __restrict__ qh, const short* __restrict__ kh,
    const short* __restrict__ vT, short* __restrict__ attout) {
  __shared__ short Kb[2][64 * 64];
  __shared__ short Vb[2][64 * 64];
  __shared__ short P_lds[4][16][64];  // epilogue staging only
  const int bh = blockIdx.x;
  const int p = blockIdx.y;  // 0..3
  const int t = threadIdx.x;
  const int wave = t >> 6, lane = t & 63, quad = lane >> 4, l15 = lane & 15;
  const short* q_head = qh + (long)bh * 1024 * 64;
  const short* k_head = kh + (long)bh * 1024 * 64;
  const short* v_head = vT + (long)bh * 64 * 1024;
  const int b_ = bh >> 4, h_ = bh & 15;

  const int qt[4] = {p, 7 - p, 8 + p, 15 - p};  // ascending

  auto stage = [&](int kt, int buf) {
    const int kk0 = kt * 64;
#pragma unroll
    for (int i = 0; i < 2; ++i) {
      int s = i * 256 + t;
      int row = s >> 3, cg = (s & 7) ^ (row & 7);
      gl2lds16(&Kb[buf][s * 8], k_head + (kk0 + row) * 64 + cg * 8);
    }
#pragma unroll
    for (int i = 0; i < 2; ++i) {
      int s = i * 256 + t;
      int row = s >> 3, cg = (s & 7) ^ (row & 7);
      gl2lds16(&Vb[buf][s * 8], v_head + row * 1024 + kk0 + cg * 8);
    }
  };

  bf16x8 qf[4][2];
#pragma unroll
  for (int i = 0; i < 4; ++i) {
    int qb = qt[i] * 64 + wave * 16;
#pragma unroll
    for (int s = 0; s < 2; ++s)
      qf[i][s] = *(const bf16x8*)(q_head + (qb + l15) * 64 + s * 32 + quad * 8);
  }

  float l[4] = {};
  f32x4 o[4][4] = {};

  stage(0, 0);
  __syncthreads();

  const int nkt = qt[3] + 1;  // 16 - p

#pragma unroll 1
  for (int kt = 0; kt < nkt; ++kt) {
    const int buf = kt & 1;
    const short* Kt = Kb[buf];
    const short* Vt = Vb[buf];

    // K and V fragments: identical identity-layout b128 reads (V is
    // sigma-permuted in memory, matching the P-operand permutation pi).
    bf16x8 kfr[4][2], vfr[4][2];
#pragma unroll
    for (int jj = 0; jj < 4; ++jj) {
      int row = jj * 16 + l15;
#pragma unroll
      for (int s = 0; s < 2; ++s) {
        int off = ((s * 4 + quad) ^ (row & 7)) * 8;
        kfr[jj][s] = *(const bf16x8*)(Kt + row * 64 + off);
        vfr[jj][s] = *(const bf16x8*)(Vt + row * 64 + off);
      }
    }

    if (kt + 1 < nkt) stage(kt + 1, buf ^ 1);  // overlaps with compute below

#pragma unroll
    for (int i = 0; i < 4; ++i) {
      if (kt <= qt[i]) {
        // swapped QK: lane (l15,quad) holds S[q=l15-row][key jj*16+quad*4+r]
        f32x4 s4[4] = {};
#pragma unroll
        for (int jj = 0; jj < 4; ++jj) {
          s4[jj] = __builtin_amdgcn_mfma_f32_16x16x32_bf16(kfr[jj][0], qf[i][0],
                                                           s4[jj], 0, 0, 0);
          s4[jj] = __builtin_amdgcn_mfma_f32_16x16x32_bf16(kfr[jj][1], qf[i][1],
                                                           s4[jj], 0, 0, 0);
        }
        // softmax: q already carries 0.125*log2e -> exp2 direct
        float ev[4][4];
        float ls = 0.f;
        if (kt == qt[i]) {  // diagonal tile: causal mask (uniform branch)
          const int qg = qt[i] * 64 + wave * 16 + l15;
#pragma unroll
          for (int jj = 0; jj < 4; ++jj) {
            const int kb = kt * 64 + jj * 16 + quad * 4;
#pragma unroll
            for (int r = 0; r < 4; ++r) {
              float e = __builtin_amdgcn_exp2f(s4[jj][r]);
              if (kb + r > qg) e = 0.f;
              ev[jj][r] = e;
              ls += e;
            }
          }
        } else {
#pragma unroll
          for (int jj = 0; jj < 4; ++jj)
#pragma unroll
            for (int r = 0; r < 4; ++r) {
              float e = __builtin_amdgcn_exp2f(s4[jj][r]);
              ev[jj][r] = e;
              ls += e;
            }
        }
        l[i] += ls;
        // pi-permuted P pack: slot (s,quad,4cs+r) = key (2s+cs)*16+quad*4+r
        int4 pd0, pd1;
        pd0.x = (int)cvtpk(ev[0][0], ev[0][1]);
        pd0.y = (int)cvtpk(ev[0][2], ev[0][3]);
        pd0.z = (int)cvtpk(ev[1][0], ev[1][1]);
        pd0.w = (int)cvtpk(ev[1][2], ev[1][3]);
        pd1.x = (int)cvtpk(ev[2][0], ev[2][1]);
        pd1.y = (int)cvtpk(ev[2][2], ev[2][3]);
        pd1.z = (int)cvtpk(ev[3][0], ev[3][1]);
        pd1.w = (int)cvtpk(ev[3][2], ev[3][3]);
        bf16x8 pf0 = __builtin_bit_cast(bf16x8, pd0);
        bf16x8 pf1 = __builtin_bit_cast(bf16x8, pd1);
#pragma unroll
        for (int dj = 0; dj < 4; ++dj) {
          o[i][dj] = __builtin_amdgcn_mfma_f32_16x16x32_bf16(pf0, vfr[dj][0],
                                                             o[i][dj], 0, 0, 0);
          o[i][dj] = __builtin_amdgcn_mfma_f32_16x16x32_bf16(pf1, vfr[dj][1],
                                                             o[i][dj], 0, 0, 0);
        }
      }
    }
    __syncthreads();  // releases buf for re-stage; drains prefetch vmcnt
  }

  // deferred l reductions: sum partial row-sums across the 4 quads
#pragma unroll
  for (int i = 0; i < 4; ++i) {
    l[i] += __shfl_xor(l[i], 16);
    l[i] += __shfl_xor(l[i], 32);
  }

  // epilogue: per tile, C-layout -> rows via P_lds, then cached 16B stores.
  const int erow = lane >> 3, ech = lane & 7;
#pragma unroll
  for (int i = 0; i < 4; ++i) {
    float inv[4];
#pragma unroll
    for (int r = 0; r < 4; ++r) {
      float lr = __shfl(l[i], quad * 4 + r);  // row-sum lives in lane l15=row
      inv[r] = __builtin_amdgcn_rcpf(lr);
    }
    const int qb = qt[i] * 64 + wave * 16;
#pragma unroll
    for (int dj = 0; dj < 4; ++dj) {
      int ch = dj * 2 + (l15 >> 3), co = l15 & 7;
#pragma unroll
      for (int r = 0; r < 4; ++r) {
        int row = quad * 4 + r;
        P_lds[wave][row][(ch ^ (row & 7)) * 8 + co] = f2b(o[i][dj][r] * inv[r]);
      }
    }
    asm volatile("s_waitcnt lgkmcnt(0)" ::: "memory");
#pragma unroll
    for (int pass = 0; pass < 2; ++pass) {
      int row = pass * 8 + erow;
      bf16x8 v = *(const bf16x8*)(&P_lds[wave][row][(ech ^ (row & 7)) * 8]);
      long g = (long)b_ * 1024 + qb + row;
      *(bf16x8*)(attout + g * 1024 + h_ * 64 + ech * 8) = v;
    }
    asm volatile("s_waitcnt lgkmcnt(0)" ::: "memory");  // reads before next writes
  }
}

// ---------------- launch ----------------

extern "C" void kernel_launch(void* const* d_in, const int* in_sizes, int n_in,
                              void* d_out, int out_size, void* d_ws,
                              size_t ws_size, hipStream_t stream) {
  const float* x = (const float*)d_in[0];
  const float* W_attn = (const float*)d_in[2];
  const float* b_attn = (const float*)d_in[3];
  const float* W_proj = (const float*)d_in[4];
  const float* b_proj = (const float*)d_in[5];
  float* out = (float*)d_out;

  char* ws = (char*)d_ws;
  const size_t MB = 1u << 20;
  short* xb = (short*)(ws);              // 16 MB [0,16)
  short* WaT = (short*)(ws + 16 * MB);   // 6 MB  [16,22)
  short* WpT = (short*)(ws + 22 * MB);   // 2 MB  [22,24)
  short* qh = (short*)(ws + 24 * MB);    // 16 MB [24,40)
  short* kh = (short*)(ws + 40 * MB);    // 16 MB [40,56)
  short* vT = (short*)(ws + 56 * MB);    // 16 MB [56,72)
  short* attout = xb;                    // reuse x-bf16 region

  prep_fused<<<12288, 256, 0, stream>>>(x, xb, W_attn, WaT, W_proj, WpT);
  gemm_bt<0><<<dim3(3072 / 128, 8192 / 128), 256, 0, stream>>>(
      xb, WaT, b_attn, nullptr, qh, kh, vT, 8192, 3072, 1024);
  attn_kernel<<<dim3(128, 4), 256, 0, stream>>>(qh, kh, vT, attout);
  gemm_bt<1><<<dim3(1024 / 128, 8192 / 128), 256, 0, stream>>>(
      attout, WpT, b_proj, out, nullptr, nullptr, nullptr, 8192, 1024, 1024);
}